// Round 9
// baseline (1799.770 us; speedup 1.0000x reference)
//
#include <hip/hip_runtime.h>

// SpectralSGCN2Layer:
//   sd = h @ gate_w[0,:D]; ss = h @ gate_w[0,D:]
//   alpha = tanh(sd[dst] + ss[src] + gb)
//   e = alpha * d[dst] * d[src] * w
//   z = segment_sum(h[src] * e[:,None], dst, N)
//
// Round 7: coarse 64-node buckets instead of full per-node CSR sort.
//  - bscatter appends packed (src|dstLow<<20, c) to bucket regions: writes
//    cluster on ~1.5k hot lines -> WRITE_SIZE ~= payload (16MB vs 101MB).
//  - bgather: 1 block per bucket, f32 LDS accumulators (64 rows x 128 cols,
//    two [64][65] planes, conflict-free), bf16 h-row gathers, LDS atomics,
//    one coalesced z write. Kills the 100k-wide hist+scan scaffolding.

#define NPB 64
#define NPB_SHIFT 6

// ---------------- node scores, packed with d: sdd2=(sd,d), ssd2=(ss,d) ----
__global__ void node_scores2_kernel(const float* __restrict__ h,
                                    const float* __restrict__ d,
                                    const float* __restrict__ gate_w,
                                    float2* __restrict__ sdd2,
                                    float2* __restrict__ ssd2,
                                    int n_nodes, int D) {
    int wave = (blockIdx.x * blockDim.x + threadIdx.x) >> 6;
    int lane = threadIdx.x & 63;
    if (wave >= n_nodes) return;

    const float2* hrow = reinterpret_cast<const float2*>(h + (size_t)wave * D);
    const float2* wd   = reinterpret_cast<const float2*>(gate_w);
    const float2* ws   = reinterpret_cast<const float2*>(gate_w + D);

    float2 hv = hrow[lane];
    float2 wdv = wd[lane];
    float2 wsv = ws[lane];
    float pd = hv.x * wdv.x + hv.y * wdv.y;
    float ps = hv.x * wsv.x + hv.y * wsv.y;

    #pragma unroll
    for (int off = 32; off > 0; off >>= 1) {
        pd += __shfl_xor(pd, off, 64);
        ps += __shfl_xor(ps, off, 64);
    }
    if (lane == 0) {
        float dv = d[wave];
        sdd2[wave] = make_float2(pd, dv);
        ssd2[wave] = make_float2(ps, dv);
    }
}

// ---------------- h (f32) -> hb (bf16 packed pairs, RNE) ----------------
__device__ __forceinline__ unsigned bf16_rne(float f) {
    unsigned u = __float_as_uint(f);
    return (u + 0x7fffu + ((u >> 16) & 1u)) >> 16;
}

__global__ void h2bf16_kernel(const float2* __restrict__ h2,
                              unsigned* __restrict__ hb, size_t n2) {
    size_t i = (size_t)blockIdx.x * blockDim.x + threadIdx.x;
    if (i >= n2) return;
    float2 v = h2[i];
    hb[i] = bf16_rne(v.x) | (bf16_rne(v.y) << 16);
}

// ---------------- bucket histogram of dst ----------------
__global__ void bhist_kernel(const int* __restrict__ dst,
                             int* __restrict__ bdeg, int n_edges) {
    int e = blockIdx.x * blockDim.x + threadIdx.x;
    if (e >= n_edges) return;
    atomicAdd(&bdeg[dst[e] >> NPB_SHIFT], 1);
}

// ---------------- bucket exclusive scan (single block) ----------------
__global__ void bscan_kernel(const int* __restrict__ bdeg,
                             int* __restrict__ boffs,
                             int* __restrict__ bcur, int nb) {
    __shared__ int tmp[256];
    int carry = 0;
    for (int base = 0; base < nb; base += 256) {
        int i = base + threadIdx.x;
        int v = (i < nb) ? bdeg[i] : 0;
        tmp[threadIdx.x] = v;
        __syncthreads();
        #pragma unroll
        for (int off = 1; off < 256; off <<= 1) {
            int t = (threadIdx.x >= off) ? tmp[threadIdx.x - off] : 0;
            __syncthreads();
            tmp[threadIdx.x] += t;
            __syncthreads();
        }
        if (i < nb) {
            int o = tmp[threadIdx.x] - v + carry;
            boffs[i] = o;
            bcur[i]  = o;
        }
        int total = tmp[255];
        __syncthreads();
        carry += total;
    }
}

// ---------------- bucket scatter: append packed (src|dl<<20, c) ----------
// 2 edges per thread for independent latency chains.
__global__ void bscatter_kernel(const float* __restrict__ w,
                                const float* __restrict__ gate_b,
                                const int* __restrict__ src,
                                const int* __restrict__ dst,
                                const float2* __restrict__ sdd2,
                                const float2* __restrict__ ssd2,
                                int* __restrict__ bcur,
                                int2* __restrict__ payload,
                                int n_edges) {
    int i = blockIdx.x * blockDim.x + threadIdx.x;
    int half = (n_edges + 1) >> 1;
    float gb = gate_b[0];
    #pragma unroll
    for (int r = 0; r < 2; ++r) {
        int e = i + r * half;
        if (e >= n_edges) break;
        int s = src[e];
        int t = dst[e];
        float2 a  = sdd2[t];
        float2 b2 = ssd2[s];
        float alpha = tanhf(a.x + b2.x + gb);
        float c = alpha * a.y * b2.y * w[e];
        int pos = atomicAdd(&bcur[t >> NPB_SHIFT], 1);
        payload[pos] = make_int2(s | ((t & (NPB - 1)) << 20), __float_as_int(c));
    }
}

// ---------------- bucket gather: LDS f32 accumulate, D==128 ----------------
// 1 block (512 thr = 8 waves) per bucket. LDS planes lx/ly[64][65]: lane i of
// row dl hits bank (dl+i)%32 -> 2 lanes/bank = free. 4 blocks/CU (33.3KB LDS).
__global__ __launch_bounds__(512) void bgather_kernel(
        const unsigned* __restrict__ hb,
        const int* __restrict__ boffs,
        const int* __restrict__ bdeg,
        const int2* __restrict__ payload,
        float* __restrict__ z,
        int n_nodes) {
    __shared__ float lx[NPB][65];
    __shared__ float ly[NPB][65];
    int b = blockIdx.x;
    int node0 = b << NPB_SHIFT;
    int nlocal = min(NPB, n_nodes - node0);
    int tid = threadIdx.x;

    for (int idx = tid; idx < NPB * 65; idx += 512) {
        (&lx[0][0])[idx] = 0.f;
        (&ly[0][0])[idx] = 0.f;
    }
    __syncthreads();

    int beg = boffs[b];
    int cnt = bdeg[b];
    int wid  = tid >> 6;
    int lane = tid & 63;

    int k = wid;
    for (; k + 8 < cnt; k += 16) {
        int2 p0 = payload[beg + k];
        int2 p1 = payload[beg + k + 8];
        unsigned v0 = hb[(size_t)(p0.x & 0xFFFFF) * 64 + lane];
        unsigned v1 = hb[(size_t)(p1.x & 0xFFFFF) * 64 + lane];
        float c0 = __int_as_float(p0.y);
        float c1 = __int_as_float(p1.y);
        int d0 = (p0.x >> 20) & (NPB - 1);
        int d1 = (p1.x >> 20) & (NPB - 1);
        atomicAdd(&lx[d0][lane], c0 * __uint_as_float(v0 << 16));
        atomicAdd(&ly[d0][lane], c0 * __uint_as_float(v0 & 0xffff0000u));
        atomicAdd(&lx[d1][lane], c1 * __uint_as_float(v1 << 16));
        atomicAdd(&ly[d1][lane], c1 * __uint_as_float(v1 & 0xffff0000u));
    }
    for (; k < cnt; k += 8) {
        int2 p0 = payload[beg + k];
        unsigned v0 = hb[(size_t)(p0.x & 0xFFFFF) * 64 + lane];
        float c0 = __int_as_float(p0.y);
        int d0 = (p0.x >> 20) & (NPB - 1);
        atomicAdd(&lx[d0][lane], c0 * __uint_as_float(v0 << 16));
        atomicAdd(&ly[d0][lane], c0 * __uint_as_float(v0 & 0xffff0000u));
    }
    __syncthreads();

    // write out nlocal rows x 128 cols, coalesced
    for (int idx = tid; idx < (nlocal << 7); idx += 512) {
        int row = idx >> 7;
        int col = idx & 127;
        float val = (col & 1) ? ly[row][col >> 1] : lx[row][col >> 1];
        z[((size_t)(node0 + row) << 7) + col] = val;
    }
}

// ---------------- Fallback: per-edge atomic scatter (packed inputs) -------
__global__ void edge_scatter_kernel(const float* __restrict__ h,
                                    const float* __restrict__ w,
                                    const float* __restrict__ gate_b,
                                    const int* __restrict__ src,
                                    const int* __restrict__ dst,
                                    const float2* __restrict__ sdd2,
                                    const float2* __restrict__ ssd2,
                                    float* __restrict__ z,
                                    int n_edges, int D) {
    int wave = (blockIdx.x * blockDim.x + threadIdx.x) >> 6;
    int lane = threadIdx.x & 63;
    if (wave >= n_edges) return;
    int s = src[wave];
    int t = dst[wave];
    float2 a  = sdd2[t];
    float2 b2 = ssd2[s];
    float alpha = tanhf(a.x + b2.x + gate_b[0]);
    float c = alpha * a.y * b2.y * w[wave];
    float2 hv = reinterpret_cast<const float2*>(h + (size_t)s * D)[lane];
    float* zr = z + (size_t)t * D + lane * 2;
    __hip_atomic_fetch_add(zr,     hv.x * c, __ATOMIC_RELAXED, __HIP_MEMORY_SCOPE_AGENT);
    __hip_atomic_fetch_add(zr + 1, hv.y * c, __ATOMIC_RELAXED, __HIP_MEMORY_SCOPE_AGENT);
}

extern "C" void kernel_launch(void* const* d_in, const int* in_sizes, int n_in,
                              void* d_out, int out_size, void* d_ws, size_t ws_size,
                              hipStream_t stream) {
    const float* h      = (const float*)d_in[0];
    const float* d      = (const float*)d_in[1];
    const float* w      = (const float*)d_in[2];
    const float* gate_w = (const float*)d_in[3];
    const float* gate_b = (const float*)d_in[4];
    const int*   src    = (const int*)d_in[5];
    const int*   dst    = (const int*)d_in[6];
    float*       z      = (float*)d_out;

    const int n_nodes = in_sizes[1];
    const int n_edges = in_sizes[2];
    const int D       = in_sizes[3] / 2;

    const int NBUK = (n_nodes + NPB - 1) >> NPB_SHIFT;

    // Workspace layout:
    // sdd2[N] f2 | ssd2[N] f2 | bdeg[NBUK] | boffs[NBUK] | bcur[NBUK] | pad8 |
    // payload[E] int2 | hb[N*D/2] u32
    size_t off_sdd2 = 0;
    size_t off_ssd2 = off_sdd2 + (size_t)n_nodes * 8;
    size_t off_bdeg = off_ssd2 + (size_t)n_nodes * 8;
    size_t off_boff = off_bdeg + (size_t)NBUK * 4;
    size_t off_bcur = off_boff + (size_t)NBUK * 4;
    size_t off_pay  = (off_bcur + (size_t)NBUK * 4 + 7) & ~(size_t)7;
    size_t off_hb   = off_pay + (size_t)n_edges * 8;
    size_t need     = off_hb + (size_t)n_nodes * (D / 2) * 4;

    char* base = (char*)d_ws;
    float2* sdd2    = (float2*)(base + off_sdd2);
    float2* ssd2    = (float2*)(base + off_ssd2);
    int*    bdeg    = (int*)(base + off_bdeg);
    int*    boffs   = (int*)(base + off_boff);
    int*    bcur    = (int*)(base + off_bcur);
    int2*   payload = (int2*)(base + off_pay);
    unsigned* hb    = (unsigned*)(base + off_hb);

    // node scores (both paths need them)
    {
        int blocks = (n_nodes + 3) / 4;  // 4 waves/block
        node_scores2_kernel<<<blocks, 256, 0, stream>>>(h, d, gate_w, sdd2, ssd2,
                                                        n_nodes, D);
    }

    if (D == 128 && need <= ws_size) {
        // bf16 conversion of h
        {
            size_t n2 = (size_t)n_nodes * (D / 2);
            int cblocks = (int)((n2 + 255) / 256);
            h2bf16_kernel<<<cblocks, 256, 0, stream>>>(
                reinterpret_cast<const float2*>(h), hb, n2);
        }
        hipMemsetAsync(bdeg, 0, (size_t)NBUK * 4, stream);

        int eblocks = (n_edges + 255) / 256;
        bhist_kernel<<<eblocks, 256, 0, stream>>>(dst, bdeg, n_edges);
        bscan_kernel<<<1, 256, 0, stream>>>(bdeg, boffs, bcur, NBUK);
        {
            int half = (n_edges + 1) >> 1;
            int sblocks = (half + 255) / 256;
            bscatter_kernel<<<sblocks, 256, 0, stream>>>(w, gate_b, src, dst,
                                                         sdd2, ssd2, bcur,
                                                         payload, n_edges);
        }
        bgather_kernel<<<NBUK, 512, 0, stream>>>(hb, boffs, bdeg, payload,
                                                 z, n_nodes);
    } else {
        // Fallback: atomic scatter path.
        hipMemsetAsync(d_out, 0, (size_t)out_size * sizeof(float), stream);
        int blocks = (n_edges + 3) / 4;
        edge_scatter_kernel<<<blocks, 256, 0, stream>>>(h, w, gate_b, src, dst,
                                                        sdd2, ssd2, z, n_edges, D);
    }
}